// Round 5
// baseline (227.220 us; speedup 1.0000x reference)
//
#include <hip/hip_runtime.h>
#include <math.h>

#define HEADS 8
#define HIDC  32
#define MODES 8
#define IN_CH 4
#define SEQ   32
#define NS    64      // B*SEQ samples
#define HD    256     // HEADS*HIDC
#define NM    64      // MODES*MODES
#define NPIX  4096    // 64*64
#define TWO_PI_D 6.283185307179586476925286766559

__device__ __forceinline__ float2 f2(float a, float b){ return make_float2(a,b); }

// ---------------------------------------------------------------------------
// K1: partial forward DFT of v: per field [64][64] -> 8x8 low modes (fp32).
// ---------------------------------------------------------------------------
__global__ __launch_bounds__(256) void fwd_dft_kernel(const float* __restrict__ src,
                                                      float2* __restrict__ dst){
  int f = blockIdx.x;
  const float* fld = src + (size_t)f * NPIX;
  __shared__ float  s_fld[64*65];
  __shared__ float2 s_cs[64];
  __shared__ float2 s_a1[64][8];
  int tid = threadIdx.x;
  for (int k = tid; k < NPIX; k += 256) s_fld[(k>>6)*65 + (k&63)] = fld[k];
  if (tid < 64){ double sv, cv; sincos(TWO_PI_D * tid / 64.0, &sv, &cv); s_cs[tid] = f2((float)cv,(float)sv); }
  __syncthreads();
  for (int o = tid; o < 512; o += 256){
    int y = o >> 3, kx = o & 7;
    const float* row = s_fld + y*65;
    float sr = 0.f, si = 0.f;
    for (int x = 0; x < 64; ++x){
      float2 cs = s_cs[(kx*x) & 63];
      float v = row[x];
      sr += v * cs.x; si -= v * cs.y;
    }
    s_a1[y][kx] = f2(sr, si);
  }
  __syncthreads();
  if (tid < 64){
    int ky = tid >> 3, kx = tid & 7;
    float sr = 0.f, si = 0.f;
    for (int y = 0; y < 64; ++y){
      float2 a = s_a1[y][kx];
      float2 cs = s_cs[(ky*y) & 63];
      sr += a.x*cs.x + a.y*cs.y;
      si += a.y*cs.x - a.x*cs.y;
    }
    dst[(size_t)f*NM + tid] = f2(sr, si);
  }
}

// ---------------------------------------------------------------------------
// K2: weight Grams, block per mode m; G2 pre-scaled by Parseval weight.
// ---------------------------------------------------------------------------
__global__ __launch_bounds__(256) void gram_kernel(const float* __restrict__ qwr, const float* __restrict__ qwi,
                                                   const float* __restrict__ kwr, const float* __restrict__ kwi,
                                                   float2* __restrict__ G2, float* __restrict__ Gdc){
  int m = blockIdx.x, tid = threadIdx.x;
  __shared__ float qsr[4][257], qsi[4][257], ksr[4][257], ksi[4][257];
  for (int k = tid; k < 1024; k += 256){
    int i = k >> 8, c = k & 255;
    size_t a = ((size_t)(i*256 + c))*64 + m;
    qsr[i][c] = qwr[a]; qsi[i][c] = qwi[a];
    ksr[i][c] = kwr[a]; ksi[i][c] = kwi[a];
  }
  __syncthreads();
  int kx = m & 7, ky = m >> 3;
  float w = (kx >= 1) ? 2.0f : ((ky >= 1) ? 0.5f : 0.0f);
  for (int e = tid; e < 1024; e += 256){
    int P = e >> 7, T = (e >> 4) & 7, i = (e >> 2) & 3, j = e & 3;
    float grr=0.f, gri=0.f, gir=0.f, gii=0.f;
    for (int d = 0; d < 32; ++d){
      float ar = qsr[i][P*32+d], ai = qsi[i][P*32+d];
      float br = ksr[j][T*32+d], bi = ksi[j][T*32+d];
      grr += ar*br; gri += ar*bi; gir += ai*br; gii += ai*bi;
    }
    G2[(size_t)(((m*8+P)*4+i)*4+j)*8 + T] = f2(w*(grr+gii), w*(gir-gri));
    if (m == 0){
      int o = ((P*4+i)*4+j)*8 + T;
      Gdc[o] = grr; Gdc[1024+o] = gri; Gdc[2048+o] = gir; Gdc[3072+o] = gii;
    }
  }
}

// ---------------------------------------------------------------------------
// K3: attention logits via Parseval + softmax -> A.
// ---------------------------------------------------------------------------
__global__ __launch_bounds__(256) void attn_kernel(const float2* __restrict__ Vf,
                                                   const float2* __restrict__ G2,
                                                   const float* __restrict__ Gdc,
                                                   float* __restrict__ A){
  int bx = blockIdx.x;                 // (b<<8)|(hh<<5)|s
  int s = bx & 31;
  int base = ((bx >> 8) * 32) + (((bx >> 5) & 7) * 4);
  int tid = threadIdx.x;
  int t = tid & 31, mc = tid >> 5;
  __shared__ float2 s_vf[4][IN_CH][64];
  __shared__ float  s_part[8][33];
  for (int k = tid; k < 4*IN_CH*64; k += 256){
    int m = k & 63, c = (k>>6)&3, smp = k>>8;
    s_vf[smp][c][m] = Vf[((size_t)(base+smp)*IN_CH + c)*NM + m];
  }
  __syncthreads();
  int sg = s >> 3, P = s & 7;
  int tg = t >> 3, T = t & 7;
  float acc = 0.f;
  for (int mm = 0; mm < 8; ++mm){
    int m = mc*8 + mm;
    const float2* g = G2 + (size_t)((m*8+P)*16)*8 + T;
    float sub = 0.f;
    for (int i = 0; i < 4; ++i){
      float2 a = s_vf[sg][i][m];
      for (int j = 0; j < 4; ++j){
        float2 b = s_vf[tg][j][m];
        float zr = a.x*b.x + a.y*b.y;
        float zi = a.y*b.x - a.x*b.y;
        float2 gv = g[(size_t)(i*4+j)*8];
        sub += zr*gv.x - zi*gv.y;
      }
    }
    acc += sub;
  }
  if (mc == 0){
    float sub = 0.f;
    for (int i = 0; i < 4; ++i){
      float2 a = s_vf[sg][i][0];
      for (int j = 0; j < 4; ++j){
        float2 b = s_vf[tg][j][0];
        int o = ((P*4+i)*4+j)*8 + T;
        sub += a.x*b.x*Gdc[o] - a.x*b.y*Gdc[1024+o]
             - a.y*b.x*Gdc[2048+o] + a.y*b.y*Gdc[3072+o];
      }
    }
    acc += sub;
  }
  s_part[mc][t] = acc;
  __syncthreads();
  if (tid < 32){
    float l2 = 0.f;
    for (int k = 0; k < 8; ++k) l2 += s_part[k][tid];
    l2 *= 0.5f / (4096.0f * 4096.0f);
    float mx = l2;
    for (int off = 16; off; off >>= 1) mx = fmaxf(mx, __shfl_xor(mx, off, 32));
    float e = expf(l2 - mx);
    float sm = e;
    for (int off = 16; off; off >>= 1) sm += __shfl_xor(sm, off, 32);
    A[(size_t)bx*32 + tid] = e / sm;
  }
}

// ---------------------------------------------------------------------------
// K4: fused vconv + attention-apply. Block per (b,hh,m-pair). Uf[n][m][c].
// ---------------------------------------------------------------------------
__global__ __launch_bounds__(256) void uspec_kernel(const float2* __restrict__ Vf,
                                                    const float* __restrict__ vwr, const float* __restrict__ vwi,
                                                    const float* __restrict__ A,
                                                    float2* __restrict__ Uf){
  int bid = blockIdx.x;                // b*256 + hh*32 + mg
  int mg = bid & 31, hh = (bid >> 5) & 7, b = bid >> 8;
  int m0 = mg*2;
  int nbase = b*32 + hh*4;
  int tid = threadIdx.x;
  __shared__ float2 s_vw[4][2][256];
  __shared__ float2 s_vv[4][2][256];
  __shared__ float  s_A[32][33];
  __shared__ float2 s_vf[4][4][2];
  for (int k = tid; k < 2048; k += 256){
    int i = k >> 9, mm = (k >> 8) & 1, c = k & 255;
    size_t a = ((size_t)i*256 + c)*64 + m0 + mm;
    s_vw[i][mm][c] = f2(vwr[a], vwi[a]);
  }
  for (int k = tid; k < 1024; k += 256)
    s_A[k>>5][k&31] = A[(size_t)((b*8+hh)*32 + (k>>5))*32 + (k&31)];
  if (tid < 32){
    int smp = tid >> 3, i = (tid >> 1) & 3, mm = tid & 1;
    s_vf[smp][i][mm] = Vf[((size_t)(nbase+smp)*4 + i)*64 + m0 + mm];
  }
  __syncthreads();
  for (int k = tid; k < 2048; k += 256){
    int smp = k >> 9, mm = (k >> 8) & 1, c = k & 255;
    float sr = 0.f, si = 0.f;
    for (int i = 0; i < 4; ++i){
      float2 v = s_vf[smp][i][mm];
      float2 w = s_vw[i][mm][c];
      sr += v.x*w.x - v.y*w.y;
      si += v.x*w.y + v.y*w.x;
    }
    s_vv[smp][mm][c] = f2(sr, si);
  }
  __syncthreads();
  int sg = tid >> 5, d = tid & 31;
  float2 acc[4][2];
  for (int ss = 0; ss < 4; ++ss)
    for (int mm = 0; mm < 2; ++mm) acc[ss][mm] = f2(0.f, 0.f);
  for (int tt = 0; tt < 32; ++tt){
    int tg = tt >> 3, c = (tt & 7)*32 + d;
    float a0 = s_A[sg*4+0][tt], a1 = s_A[sg*4+1][tt];
    float a2 = s_A[sg*4+2][tt], a3 = s_A[sg*4+3][tt];
    for (int mm = 0; mm < 2; ++mm){
      float2 v = s_vv[tg][mm][c];
      acc[0][mm].x += a0*v.x; acc[0][mm].y += a0*v.y;
      acc[1][mm].x += a1*v.x; acc[1][mm].y += a1*v.y;
      acc[2][mm].x += a2*v.x; acc[2][mm].y += a2*v.y;
      acc[3][mm].x += a3*v.x; acc[3][mm].y += a3*v.y;
    }
  }
  for (int ss = 0; ss < 4; ++ss){
    int n = b*32 + sg*4 + ss;
    for (int mm = 0; mm < 2; ++mm)
      Uf[((size_t)n*64 + m0 + mm)*256 + hh*32 + d] = acc[ss][mm];
  }
}

// ---------------------------------------------------------------------------
// K4b: transpose u1w -> [m][c][o1] float4 {pr*wr, pi*wi, pr*wi, pi*wr}
// (Hermitian projection folded into the weights).
// ---------------------------------------------------------------------------
__global__ __launch_bounds__(256) void u1t_kernel(const float* __restrict__ u1wr,
                                                  const float* __restrict__ u1wi,
                                                  float4* __restrict__ u1wT){
  int t = blockIdx.x*256 + threadIdx.x;   // 524288
  int o1 = t & 31, c = (t>>5) & 255, m = t >> 13;
  float pr = ((m & 7)==0 && m) ? 0.5f : 1.0f;
  float pi = m ? pr : 0.0f;
  size_t src = ((size_t)c*32 + o1)*64 + m;
  float wr = u1wr[src], wi = u1wi[src];
  u1wT[t] = make_float4(pr*wr, pi*wi, pr*wi, pi*wr);
}

// ---------------------------------------------------------------------------
// K5: channel mixes. U1f = P(Uf) x u1w (projection folded in u1wT), S1f = Uf x s1w.
// Block per (n, 4-mode group); one output pair per thread.
// ---------------------------------------------------------------------------
__global__ __launch_bounds__(128) void mix1_kernel(const float2* __restrict__ Uf,
                                                   const float4* __restrict__ u1wT,
                                                   const float* __restrict__ s1w,
                                                   float2* __restrict__ U1f, float2* __restrict__ S1f){
  int n = blockIdx.x >> 4, mg = blockIdx.x & 15, m0 = mg*4;
  int tid = threadIdx.x;
  __shared__ float2 s_u[4][256];
  for (int k = tid; k < 1024; k += 128){
    int mm = k >> 8, c = k & 255;
    s_u[mm][c] = Uf[((size_t)n*64 + m0 + mm)*256 + c];
  }
  __syncthreads();
  int o1 = tid & 31, mm = tid >> 5;
  int m = m0 + mm;
  const float4* wp = u1wT + (size_t)m*256*32 + o1;
  const float* swp = s1w + o1*256;
  float2 au = f2(0.f,0.f), asv = f2(0.f,0.f);
  #pragma unroll 8
  for (int c = 0; c < 256; ++c){
    float2 u = s_u[mm][c];
    float4 w = wp[(size_t)c*32];
    float sw = swp[c];
    au.x  += u.x*w.x - u.y*w.y;
    au.y  += u.x*w.z + u.y*w.w;
    asv.x += u.x*sw;
    asv.y += u.y*sw;
  }
  size_t ob = ((size_t)n*32 + o1)*64 + m;
  U1f[ob] = au; S1f[ob] = asv;
}

// ---------------------------------------------------------------------------
// K6: x1 = gelu(irfft(U1f)) + irfft(S1f) + s1b, fused with fwd DFT -> X1f.
// Register-hoisted twiddles (x fixed per thread), b128 row loads.
// ---------------------------------------------------------------------------
__global__ __launch_bounds__(256) void x1dft_kernel(const float2* __restrict__ U1f,
                                                    const float2* __restrict__ S1f,
                                                    const float* __restrict__ s1b,
                                                    float* __restrict__ x1,
                                                    float2* __restrict__ X1f){
  int f = blockIdx.x, o1 = f & 31, tid = threadIdx.x;
  __shared__ float2 s_e[64][8];       // s_e[a][b] = (cos,sin)(2*pi*((a*b)&63)/64)
  __shared__ float2 s_gu[64], s_gs[64];
  __shared__ float2 s_tu[64][8], s_ts[64][8];
  __shared__ float  s_fld[64*68];     // padded rows (68) for conflict-free b128
  __shared__ float2 s_a1[64][8];
  for (int e = tid; e < 512; e += 256){
    int a = e >> 3, b = e & 7;
    double sv, cv; sincos(TWO_PI_D * ((a*b) & 63) / 64.0, &sv, &cv);
    s_e[a][b] = f2((float)cv, (float)sv);
  }
  if (tid >= 128 && tid < 192) s_gu[tid-128] = U1f[(size_t)f*NM + tid-128];
  else if (tid >= 192) s_gs[tid-192] = S1f[(size_t)f*NM + tid-192];
  __syncthreads();
  // phase A: T[y][kx] = wf * sum_ky G[ky*8+kx] e^{+i 2pi ky y/64}
  for (int o = tid; o < 512; o += 256){
    int y = o >> 3, kx = o & 7;
    float wf = (kx ? 2.0f : 1.0f) * (1.0f/4096.0f);
    float ar=0.f, ai=0.f, br=0.f, bi=0.f;
    for (int ky = 0; ky < 8; ++ky){
      float2 cs = s_e[y][ky];
      float2 gu = s_gu[ky*8+kx], gs = s_gs[ky*8+kx];
      ar += gu.x*cs.x - gu.y*cs.y;  ai += gu.x*cs.y + gu.y*cs.x;
      br += gs.x*cs.x - gs.y*cs.y;  bi += gs.x*cs.y + gs.y*cs.x;
    }
    s_tu[y][kx] = f2(ar*wf, ai*wf);
    s_ts[y][kx] = f2(br*wf, bi*wf);
  }
  __syncthreads();
  // phase B: pixels. x = tid&63 fixed per thread -> hoist twiddles to regs.
  int xx = tid & 63;
  float2 ce[8];
  {
    const float4* ep = (const float4*)&s_e[xx][0];
    float4 e0 = ep[0], e1 = ep[1], e2 = ep[2], e3 = ep[3];
    ce[0]=f2(e0.x,e0.y); ce[1]=f2(e0.z,e0.w);
    ce[2]=f2(e1.x,e1.y); ce[3]=f2(e1.z,e1.w);
    ce[4]=f2(e2.x,e2.y); ce[5]=f2(e2.z,e2.w);
    ce[6]=f2(e3.x,e3.y); ce[7]=f2(e3.z,e3.w);
  }
  float bias = s1b[o1];
  float* dst = x1 + (size_t)f*NPIX;
  for (int i = 0; i < 16; ++i){
    int p = i*256 + tid;
    int y = p >> 6;                    // wave-uniform
    const float4* tp = (const float4*)&s_tu[y][0];
    float4 t0 = tp[0], t1 = tp[1], t2 = tp[2], t3 = tp[3];
    const float4* up = (const float4*)&s_ts[y][0];
    float4 u0 = up[0], u1 = up[1], u2 = up[2], u3 = up[3];
    float vu = t0.x*ce[0].x - t0.y*ce[0].y + t0.z*ce[1].x - t0.w*ce[1].y
             + t1.x*ce[2].x - t1.y*ce[2].y + t1.z*ce[3].x - t1.w*ce[3].y
             + t2.x*ce[4].x - t2.y*ce[4].y + t2.z*ce[5].x - t2.w*ce[5].y
             + t3.x*ce[6].x - t3.y*ce[6].y + t3.z*ce[7].x - t3.w*ce[7].y;
    float vs = u0.x*ce[0].x - u0.y*ce[0].y + u0.z*ce[1].x - u0.w*ce[1].y
             + u1.x*ce[2].x - u1.y*ce[2].y + u1.z*ce[3].x - u1.w*ce[3].y
             + u2.x*ce[4].x - u2.y*ce[4].y + u2.z*ce[5].x - u2.w*ce[5].y
             + u3.x*ce[6].x - u3.y*ce[6].y + u3.z*ce[7].x - u3.w*ce[7].y;
    float g = 0.5f * vu * (1.0f + erff(vu * 0.70710678f));
    float val = g + vs + bias;
    dst[p] = val;
    s_fld[y*68 + xx] = val;
  }
  __syncthreads();
  // fwd DFT stage 1 (e^{-i}): b128 row reads, conflict-free (68-pad).
  for (int o = tid; o < 512; o += 256){
    int y = o >> 3, kx = o & 7;
    const float4* row = (const float4*)&s_fld[y*68];
    float sr = 0.f, si = 0.f;
    for (int x4 = 0; x4 < 16; ++x4){
      float4 v = row[x4];
      int xb = x4*4;
      float2 c0 = s_e[xb+0][kx], c1 = s_e[xb+1][kx];
      float2 c2 = s_e[xb+2][kx], c3 = s_e[xb+3][kx];
      sr += v.x*c0.x + v.y*c1.x + v.z*c2.x + v.w*c3.x;
      si -= v.x*c0.y + v.y*c1.y + v.z*c2.y + v.w*c3.y;
    }
    s_a1[y][kx] = f2(sr, si);
  }
  __syncthreads();
  if (tid < 64){
    int ky = tid >> 3, kx = tid & 7;
    float sr = 0.f, si = 0.f;
    for (int y = 0; y < 64; ++y){
      float2 a = s_a1[y][kx];
      float2 cs = s_e[y][ky];
      sr += a.x*cs.x + a.y*cs.y;
      si += a.y*cs.x - a.x*cs.y;
    }
    X1f[(size_t)f*NM + tid] = f2(sr, si);
  }
}

// ---------------------------------------------------------------------------
// K7: X2f = X1f x u2w; out = irfft(X2f) + x1 x s2w + s2b. 16 tiles/sample.
// ---------------------------------------------------------------------------
__global__ __launch_bounds__(256) void final_kernel(const float2* __restrict__ X1f,
                                                    const float* __restrict__ u2wr, const float* __restrict__ u2wi,
                                                    const float* __restrict__ x1,
                                                    const float* __restrict__ s2w, const float* __restrict__ s2b,
                                                    float* __restrict__ out){
  int n = blockIdx.x >> 4, tile = blockIdx.x & 15;
  int tid = threadIdx.x;
  __shared__ float2 s_e[64][8];
  __shared__ float2 s_x2f[4][64];
  __shared__ float2 s_tmp[4][64][8];
  __shared__ float  s_w2[128];
  __shared__ float  s_b2[4];
  for (int e = tid; e < 512; e += 256){
    int a = e >> 3, b = e & 7;
    double sv, cv; sincos(TWO_PI_D * ((a*b) & 63) / 64.0, &sv, &cv);
    s_e[a][b] = f2((float)cv, (float)sv);
  }
  if (tid < 128) s_w2[tid] = s2w[tid];
  if (tid >= 128 && tid < 132) s_b2[tid-128] = s2b[tid-128];
  {
    int o2 = tid >> 6, m = tid & 63;
    float sr = 0.f, si = 0.f;
    for (int o1 = 0; o1 < 32; ++o1){
      float2 xv = X1f[((size_t)n*HIDC + o1)*NM + m];
      size_t wb = ((size_t)(o1*IN_CH + o2))*NM + m;
      float wr = u2wr[wb], wi = u2wi[wb];
      sr += xv.x*wr - xv.y*wi;
      si += xv.x*wi + xv.y*wr;
    }
    s_x2f[o2][m] = f2(sr, si);
  }
  __syncthreads();
  for (int o = tid; o < 2048; o += 256){
    int o2 = o >> 9, rem = o & 511, y = rem >> 3, kx = rem & 7;
    float wf = (kx ? 2.0f : 1.0f) * (1.0f/4096.0f);
    float tr=0.f, ti=0.f;
    for (int ky = 0; ky < 8; ++ky){
      float2 cs = s_e[y][ky];
      float2 g = s_x2f[o2][ky*8+kx];
      tr += g.x*cs.x - g.y*cs.y;
      ti += g.x*cs.y + g.y*cs.x;
    }
    s_tmp[o2][y][kx] = f2(tr*wf, ti*wf);
  }
  __syncthreads();
  int p = tile*256 + tid;
  int y = p >> 6, xx = p & 63;
  float2 ce[8];
  {
    const float4* ep = (const float4*)&s_e[xx][0];
    float4 e0 = ep[0], e1 = ep[1], e2 = ep[2], e3 = ep[3];
    ce[0]=f2(e0.x,e0.y); ce[1]=f2(e0.z,e0.w);
    ce[2]=f2(e1.x,e1.y); ce[3]=f2(e1.z,e1.w);
    ce[4]=f2(e2.x,e2.y); ce[5]=f2(e2.z,e2.w);
    ce[6]=f2(e3.x,e3.y); ce[7]=f2(e3.z,e3.w);
  }
  const float* xbase = x1 + (size_t)n*HIDC*NPIX;
  float* obase = out + (size_t)n*IN_CH*NPIX;
  float a0 = s_b2[0], a1 = s_b2[1], a2 = s_b2[2], a3 = s_b2[3];
  #pragma unroll 8
  for (int c = 0; c < 32; ++c){
    float xv = xbase[(size_t)c*NPIX + p];
    a0 += s_w2[c]*xv; a1 += s_w2[32+c]*xv; a2 += s_w2[64+c]*xv; a3 += s_w2[96+c]*xv;
  }
  float sp[4];
  #pragma unroll
  for (int o2 = 0; o2 < 4; ++o2){
    const float4* tp = (const float4*)&s_tmp[o2][y][0];
    float4 t0 = tp[0], t1 = tp[1], t2 = tp[2], t3 = tp[3];
    sp[o2] = t0.x*ce[0].x - t0.y*ce[0].y + t0.z*ce[1].x - t0.w*ce[1].y
           + t1.x*ce[2].x - t1.y*ce[2].y + t1.z*ce[3].x - t1.w*ce[3].y
           + t2.x*ce[4].x - t2.y*ce[4].y + t2.z*ce[5].x - t2.w*ce[5].y
           + t3.x*ce[6].x - t3.y*ce[6].y + t3.z*ce[7].x - t3.w*ce[7].y;
  }
  obase[p]          = a0 + sp[0];
  obase[NPIX + p]   = a1 + sp[1];
  obase[2*NPIX + p] = a2 + sp[2];
  obase[3*NPIX + p] = a3 + sp[3];
}

extern "C" void kernel_launch(void* const* d_in, const int* in_sizes, int n_in,
                              void* d_out, int out_size, void* d_ws, size_t ws_size,
                              hipStream_t stream) {
  (void)in_sizes; (void)n_in; (void)out_size; (void)ws_size;
  const float* v    = (const float*)d_in[0];
  const float* qwr  = (const float*)d_in[1];
  const float* qwi  = (const float*)d_in[2];
  const float* kwr  = (const float*)d_in[3];
  const float* kwi  = (const float*)d_in[4];
  const float* vwr  = (const float*)d_in[5];
  const float* vwi  = (const float*)d_in[6];
  const float* u1wr = (const float*)d_in[7];
  const float* u1wi = (const float*)d_in[8];
  const float* u2wr = (const float*)d_in[9];
  const float* u2wi = (const float*)d_in[10];
  const float* s1w  = (const float*)d_in[11];
  const float* s1b  = (const float*)d_in[12];
  const float* s2w  = (const float*)d_in[13];
  const float* s2b  = (const float*)d_in[14];
  float* out = (float*)d_out;

  float* ws = (float*)d_ws;
  size_t off = 0;
  float2* Vf   = (float2*)(ws + off); off += (size_t)NS*IN_CH*NM*2;     // 32768
  float2* G2   = (float2*)(ws + off); off += (size_t)65536*2;           // 131072
  float*  Gdc  =          (ws + off); off += 4096;
  float*  A    =          (ws + off); off += 16384;
  float2* Uf   = (float2*)(ws + off); off += (size_t)NS*NM*HD*2;        // 2097152
  float2* U1f  = (float2*)(ws + off); off += (size_t)NS*HIDC*NM*2;      // 262144
  float2* S1f  = (float2*)(ws + off); off += (size_t)NS*HIDC*NM*2;      // 262144
  float*  x1   =          (ws + off); off += (size_t)NS*HIDC*NPIX;      // 8388608
  float2* X1f  = (float2*)(ws + off); off += (size_t)NS*HIDC*NM*2;      // 262144
  // u1wT aliases x1: written by u1t, consumed by mix1, dead before x1dft writes x1.
  float4* u1wT = (float4*)x1;   // 524288 float4 = 8388608 floats, exact fit

  fwd_dft_kernel<<<NS*IN_CH, 256, 0, stream>>>(v, Vf);
  gram_kernel<<<64, 256, 0, stream>>>(qwr, qwi, kwr, kwi, G2, Gdc);
  u1t_kernel<<<2048, 256, 0, stream>>>(u1wr, u1wi, u1wT);
  attn_kernel<<<512, 256, 0, stream>>>(Vf, G2, Gdc, A);
  uspec_kernel<<<512, 256, 0, stream>>>(Vf, vwr, vwi, A, Uf);
  mix1_kernel<<<1024, 128, 0, stream>>>(Uf, u1wT, s1w, U1f, S1f);
  x1dft_kernel<<<NS*HIDC, 256, 0, stream>>>(U1f, S1f, s1b, x1, X1f);
  final_kernel<<<64*16, 256, 0, stream>>>(X1f, u2wr, u2wi, x1, s2w, s2b, out);
}

// Round 6
// 221.983 us; speedup vs baseline: 1.0236x; 1.0236x over previous
//
#include <hip/hip_runtime.h>
#include <math.h>

#define HEADS 8
#define HIDC  32
#define MODES 8
#define IN_CH 4
#define SEQ   32
#define NS    64      // B*SEQ samples
#define HD    256     // HEADS*HIDC
#define NM    64      // MODES*MODES
#define NPIX  4096    // 64*64
#define TWO_PI_D 6.283185307179586476925286766559

__device__ __forceinline__ float2 f2(float a, float b){ return make_float2(a,b); }

// ---------------------------------------------------------------------------
// K0: twiddle table Etab[a][b] = (cos,sin)(2*pi*((a*b)&63)/64), a<64, b<8.
// Built ONCE; hot kernels just load it (no device sincos anywhere else).
// ---------------------------------------------------------------------------
__global__ void twiddle_kernel(float2* __restrict__ Etab){
  int t = threadIdx.x;                // 512 threads
  int a = t >> 3, b = t & 7;
  double sv, cv; sincos(TWO_PI_D * ((a*b) & 63) / 64.0, &sv, &cv);
  Etab[t] = f2((float)cv, (float)sv);
}

// ---------------------------------------------------------------------------
// K1: partial forward DFT of v: per field [64][64] -> 8x8 low modes.
// ---------------------------------------------------------------------------
__global__ __launch_bounds__(256) void fwd_dft_kernel(const float* __restrict__ src,
                                                      const float2* __restrict__ Etab,
                                                      float2* __restrict__ dst){
  int f = blockIdx.x, tid = threadIdx.x;
  __shared__ float  s_fld[64*68];
  __shared__ float2 s_e[64][8];
  __shared__ float2 s_a1[64][8];
  for (int e = tid; e < 512; e += 256) ((float2*)s_e)[e] = Etab[e];
  const float4* f4 = (const float4*)(src + (size_t)f*NPIX);
  for (int k = tid; k < 1024; k += 256){
    float4 v = f4[k];
    int y = k >> 4, x4 = (k & 15)*4;
    float* row = &s_fld[y*68 + x4];
    row[0]=v.x; row[1]=v.y; row[2]=v.z; row[3]=v.w;
  }
  __syncthreads();
  for (int o = tid; o < 512; o += 256){
    int y = o >> 3, kx = o & 7;
    const float4* row = (const float4*)&s_fld[y*68];
    float sr = 0.f, si = 0.f;
    for (int x4 = 0; x4 < 16; ++x4){
      float4 v = row[x4];
      int xb = x4*4;
      float2 c0 = s_e[xb+0][kx], c1 = s_e[xb+1][kx];
      float2 c2 = s_e[xb+2][kx], c3 = s_e[xb+3][kx];
      sr += v.x*c0.x + v.y*c1.x + v.z*c2.x + v.w*c3.x;
      si -= v.x*c0.y + v.y*c1.y + v.z*c2.y + v.w*c3.y;
    }
    s_a1[y][kx] = f2(sr, si);
  }
  __syncthreads();
  if (tid < 64){
    int ky = tid >> 3, kx = tid & 7;
    float sr = 0.f, si = 0.f;
    for (int y = 0; y < 64; ++y){
      float2 a = s_a1[y][kx];
      float2 cs = s_e[y][ky];
      sr += a.x*cs.x + a.y*cs.y;
      si += a.y*cs.x - a.x*cs.y;
    }
    dst[(size_t)f*NM + tid] = f2(sr, si);
  }
}

// ---------------------------------------------------------------------------
// K2: weight Grams, block per mode m; G2 pre-scaled by Parseval weight.
// ---------------------------------------------------------------------------
__global__ __launch_bounds__(256) void gram_kernel(const float* __restrict__ qwr, const float* __restrict__ qwi,
                                                   const float* __restrict__ kwr, const float* __restrict__ kwi,
                                                   float2* __restrict__ G2, float* __restrict__ Gdc){
  int m = blockIdx.x, tid = threadIdx.x;
  __shared__ float qsr[4][257], qsi[4][257], ksr[4][257], ksi[4][257];
  for (int k = tid; k < 1024; k += 256){
    int i = k >> 8, c = k & 255;
    size_t a = ((size_t)(i*256 + c))*64 + m;
    qsr[i][c] = qwr[a]; qsi[i][c] = qwi[a];
    ksr[i][c] = kwr[a]; ksi[i][c] = kwi[a];
  }
  __syncthreads();
  int kx = m & 7, ky = m >> 3;
  float w = (kx >= 1) ? 2.0f : ((ky >= 1) ? 0.5f : 0.0f);
  for (int e = tid; e < 1024; e += 256){
    int P = e >> 7, T = (e >> 4) & 7, i = (e >> 2) & 3, j = e & 3;
    float grr=0.f, gri=0.f, gir=0.f, gii=0.f;
    for (int d = 0; d < 32; ++d){
      float ar = qsr[i][P*32+d], ai = qsi[i][P*32+d];
      float br = ksr[j][T*32+d], bi = ksi[j][T*32+d];
      grr += ar*br; gri += ar*bi; gir += ai*br; gii += ai*bi;
    }
    G2[(size_t)(((m*8+P)*4+i)*4+j)*8 + T] = f2(w*(grr+gii), w*(gir-gri));
    if (m == 0){
      int o = ((P*4+i)*4+j)*8 + T;
      Gdc[o] = grr; Gdc[1024+o] = gri; Gdc[2048+o] = gir; Gdc[3072+o] = gii;
    }
  }
}

// ---------------------------------------------------------------------------
// K3: attention logits via Parseval + softmax -> A.
// ---------------------------------------------------------------------------
__global__ __launch_bounds__(256) void attn_kernel(const float2* __restrict__ Vf,
                                                   const float2* __restrict__ G2,
                                                   const float* __restrict__ Gdc,
                                                   float* __restrict__ A){
  int bx = blockIdx.x;                 // (b<<8)|(hh<<5)|s
  int s = bx & 31;
  int base = ((bx >> 8) * 32) + (((bx >> 5) & 7) * 4);
  int tid = threadIdx.x;
  int t = tid & 31, mc = tid >> 5;
  __shared__ float2 s_vf[4][IN_CH][64];
  __shared__ float  s_part[8][33];
  for (int k = tid; k < 4*IN_CH*64; k += 256){
    int m = k & 63, c = (k>>6)&3, smp = k>>8;
    s_vf[smp][c][m] = Vf[((size_t)(base+smp)*IN_CH + c)*NM + m];
  }
  __syncthreads();
  int sg = s >> 3, P = s & 7;
  int tg = t >> 3, T = t & 7;
  float acc = 0.f;
  for (int mm = 0; mm < 8; ++mm){
    int m = mc*8 + mm;
    const float2* g = G2 + (size_t)((m*8+P)*16)*8 + T;
    float sub = 0.f;
    for (int i = 0; i < 4; ++i){
      float2 a = s_vf[sg][i][m];
      for (int j = 0; j < 4; ++j){
        float2 b = s_vf[tg][j][m];
        float zr = a.x*b.x + a.y*b.y;
        float zi = a.y*b.x - a.x*b.y;
        float2 gv = g[(size_t)(i*4+j)*8];
        sub += zr*gv.x - zi*gv.y;
      }
    }
    acc += sub;
  }
  if (mc == 0){
    float sub = 0.f;
    for (int i = 0; i < 4; ++i){
      float2 a = s_vf[sg][i][0];
      for (int j = 0; j < 4; ++j){
        float2 b = s_vf[tg][j][0];
        int o = ((P*4+i)*4+j)*8 + T;
        sub += a.x*b.x*Gdc[o] - a.x*b.y*Gdc[1024+o]
             - a.y*b.x*Gdc[2048+o] + a.y*b.y*Gdc[3072+o];
      }
    }
    acc += sub;
  }
  s_part[mc][t] = acc;
  __syncthreads();
  if (tid < 32){
    float l2 = 0.f;
    for (int k = 0; k < 8; ++k) l2 += s_part[k][tid];
    l2 *= 0.5f / (4096.0f * 4096.0f);
    float mx = l2;
    for (int off = 16; off; off >>= 1) mx = fmaxf(mx, __shfl_xor(mx, off, 32));
    float e = expf(l2 - mx);
    float sm = e;
    for (int off = 16; off; off >>= 1) sm += __shfl_xor(sm, off, 32);
    A[(size_t)bx*32 + tid] = e / sm;
  }
}

// ---------------------------------------------------------------------------
// K4: fused vconv + attention-apply. Block per (b,hh,m-pair). Uf[n][m][c].
// ---------------------------------------------------------------------------
__global__ __launch_bounds__(256) void uspec_kernel(const float2* __restrict__ Vf,
                                                    const float* __restrict__ vwr, const float* __restrict__ vwi,
                                                    const float* __restrict__ A,
                                                    float2* __restrict__ Uf){
  int bid = blockIdx.x;                // b*256 + hh*32 + mg
  int mg = bid & 31, hh = (bid >> 5) & 7, b = bid >> 8;
  int m0 = mg*2;
  int nbase = b*32 + hh*4;
  int tid = threadIdx.x;
  __shared__ float2 s_vw[4][2][256];
  __shared__ float2 s_vv[4][2][256];
  __shared__ float  s_A[32][33];
  __shared__ float2 s_vf[4][4][2];
  for (int k = tid; k < 2048; k += 256){
    int i = k >> 9, mm = (k >> 8) & 1, c = k & 255;
    size_t a = ((size_t)i*256 + c)*64 + m0 + mm;
    s_vw[i][mm][c] = f2(vwr[a], vwi[a]);
  }
  for (int k = tid; k < 1024; k += 256)
    s_A[k>>5][k&31] = A[(size_t)((b*8+hh)*32 + (k>>5))*32 + (k&31)];
  if (tid < 32){
    int smp = tid >> 3, i = (tid >> 1) & 3, mm = tid & 1;
    s_vf[smp][i][mm] = Vf[((size_t)(nbase+smp)*4 + i)*64 + m0 + mm];
  }
  __syncthreads();
  for (int k = tid; k < 2048; k += 256){
    int smp = k >> 9, mm = (k >> 8) & 1, c = k & 255;
    float sr = 0.f, si = 0.f;
    for (int i = 0; i < 4; ++i){
      float2 v = s_vf[smp][i][mm];
      float2 w = s_vw[i][mm][c];
      sr += v.x*w.x - v.y*w.y;
      si += v.x*w.y + v.y*w.x;
    }
    s_vv[smp][mm][c] = f2(sr, si);
  }
  __syncthreads();
  int sg = tid >> 5, d = tid & 31;
  float2 acc[4][2];
  for (int ss = 0; ss < 4; ++ss)
    for (int mm = 0; mm < 2; ++mm) acc[ss][mm] = f2(0.f, 0.f);
  for (int tt = 0; tt < 32; ++tt){
    int tg = tt >> 3, c = (tt & 7)*32 + d;
    float a0 = s_A[sg*4+0][tt], a1 = s_A[sg*4+1][tt];
    float a2 = s_A[sg*4+2][tt], a3 = s_A[sg*4+3][tt];
    for (int mm = 0; mm < 2; ++mm){
      float2 v = s_vv[tg][mm][c];
      acc[0][mm].x += a0*v.x; acc[0][mm].y += a0*v.y;
      acc[1][mm].x += a1*v.x; acc[1][mm].y += a1*v.y;
      acc[2][mm].x += a2*v.x; acc[2][mm].y += a2*v.y;
      acc[3][mm].x += a3*v.x; acc[3][mm].y += a3*v.y;
    }
  }
  for (int ss = 0; ss < 4; ++ss){
    int n = b*32 + sg*4 + ss;
    for (int mm = 0; mm < 2; ++mm)
      Uf[((size_t)n*64 + m0 + mm)*256 + hh*32 + d] = acc[ss][mm];
  }
}

// ---------------------------------------------------------------------------
// K4b: transpose u1w -> [m][c][o1] float4 {pr*wr, pi*wi, pr*wi, pi*wr}
// (Hermitian projection folded into the weights).
// ---------------------------------------------------------------------------
__global__ __launch_bounds__(256) void u1t_kernel(const float* __restrict__ u1wr,
                                                  const float* __restrict__ u1wi,
                                                  float4* __restrict__ u1wT){
  int t = blockIdx.x*256 + threadIdx.x;   // 524288
  int o1 = t & 31, c = (t>>5) & 255, m = t >> 13;
  float pr = ((m & 7)==0 && m) ? 0.5f : 1.0f;
  float pi = m ? pr : 0.0f;
  size_t src = ((size_t)c*32 + o1)*64 + m;
  float wr = u1wr[src], wi = u1wi[src];
  u1wT[t] = make_float4(pr*wr, pi*wi, pr*wi, pi*wr);
}

// ---------------------------------------------------------------------------
// K5: channel mixes. U1f = P(Uf) x u1w, S1f = Uf x s1w.
// ---------------------------------------------------------------------------
__global__ __launch_bounds__(128) void mix1_kernel(const float2* __restrict__ Uf,
                                                   const float4* __restrict__ u1wT,
                                                   const float* __restrict__ s1w,
                                                   float2* __restrict__ U1f, float2* __restrict__ S1f){
  int n = blockIdx.x >> 4, mg = blockIdx.x & 15, m0 = mg*4;
  int tid = threadIdx.x;
  __shared__ float2 s_u[4][256];
  for (int k = tid; k < 1024; k += 128){
    int mm = k >> 8, c = k & 255;
    s_u[mm][c] = Uf[((size_t)n*64 + m0 + mm)*256 + c];
  }
  __syncthreads();
  int o1 = tid & 31, mm = tid >> 5;
  int m = m0 + mm;
  const float4* wp = u1wT + (size_t)m*256*32 + o1;
  const float* swp = s1w + o1*256;
  float2 au = f2(0.f,0.f), asv = f2(0.f,0.f);
  #pragma unroll 8
  for (int c = 0; c < 256; ++c){
    float2 u = s_u[mm][c];
    float4 w = wp[(size_t)c*32];
    float sw = swp[c];
    au.x  += u.x*w.x - u.y*w.y;
    au.y  += u.x*w.z + u.y*w.w;
    asv.x += u.x*sw;
    asv.y += u.y*sw;
  }
  size_t ob = ((size_t)n*32 + o1)*64 + m;
  U1f[ob] = au; S1f[ob] = asv;
}

// ---------------------------------------------------------------------------
// K6: Xg = DFT8x8( gelu( irfft(U1f) ) ), all in LDS — no pixel field to HBM.
// ---------------------------------------------------------------------------
__global__ __launch_bounds__(256) void xg_kernel(const float2* __restrict__ Etab,
                                                 const float2* __restrict__ U1f,
                                                 float2* __restrict__ Xg){
  int f = blockIdx.x, tid = threadIdx.x;
  __shared__ float2 s_e[64][8];
  __shared__ float2 s_gu[64];
  __shared__ float2 s_tu[64][8];
  __shared__ float  s_fld[64*68];
  __shared__ float2 s_a1[64][8];
  for (int e = tid; e < 512; e += 256) ((float2*)s_e)[e] = Etab[e];
  if (tid < 64) s_gu[tid] = U1f[(size_t)f*NM + tid];
  __syncthreads();
  for (int o = tid; o < 512; o += 256){
    int y = o >> 3, kx = o & 7;
    float wf = (kx ? 2.0f : 1.0f) * (1.0f/4096.0f);
    float ar=0.f, ai=0.f;
    for (int ky = 0; ky < 8; ++ky){
      float2 cs = s_e[y][ky];
      float2 gu = s_gu[ky*8+kx];
      ar += gu.x*cs.x - gu.y*cs.y;
      ai += gu.x*cs.y + gu.y*cs.x;
    }
    s_tu[y][kx] = f2(ar*wf, ai*wf);
  }
  __syncthreads();
  int xx = tid & 63;
  float2 ce[8];
  #pragma unroll
  for (int k = 0; k < 8; ++k) ce[k] = s_e[xx][k];
  for (int i = 0; i < 16; ++i){
    int p = i*256 + tid;
    int y = p >> 6;                    // wave-uniform
    const float4* tp = (const float4*)&s_tu[y][0];
    float4 t0 = tp[0], t1 = tp[1], t2 = tp[2], t3 = tp[3];
    float vu = t0.x*ce[0].x - t0.y*ce[0].y + t0.z*ce[1].x - t0.w*ce[1].y
             + t1.x*ce[2].x - t1.y*ce[2].y + t1.z*ce[3].x - t1.w*ce[3].y
             + t2.x*ce[4].x - t2.y*ce[4].y + t2.z*ce[5].x - t2.w*ce[5].y
             + t3.x*ce[6].x - t3.y*ce[6].y + t3.z*ce[7].x - t3.w*ce[7].y;
    float g = 0.5f * vu * (1.0f + erff(vu * 0.70710678f));
    s_fld[y*68 + xx] = g;
  }
  __syncthreads();
  for (int o = tid; o < 512; o += 256){
    int y = o >> 3, kx = o & 7;
    const float4* row = (const float4*)&s_fld[y*68];
    float sr = 0.f, si = 0.f;
    for (int x4 = 0; x4 < 16; ++x4){
      float4 v = row[x4];
      int xb = x4*4;
      float2 c0 = s_e[xb+0][kx], c1 = s_e[xb+1][kx];
      float2 c2 = s_e[xb+2][kx], c3 = s_e[xb+3][kx];
      sr += v.x*c0.x + v.y*c1.x + v.z*c2.x + v.w*c3.x;
      si -= v.x*c0.y + v.y*c1.y + v.z*c2.y + v.w*c3.y;
    }
    s_a1[y][kx] = f2(sr, si);
  }
  __syncthreads();
  if (tid < 64){
    int ky = tid >> 3, kx = tid & 7;
    float sr = 0.f, si = 0.f;
    for (int y = 0; y < 64; ++y){
      float2 a = s_a1[y][kx];
      float2 cs = s_e[y][ky];
      sr += a.x*cs.x + a.y*cs.y;
      si += a.y*cs.x - a.x*cs.y;
    }
    Xg[(size_t)f*NM + tid] = f2(sr, si);
  }
}

// ---------------------------------------------------------------------------
// K7: fused final. X1f = Xg + P(S1f) + 4096*s1b*dc; X2f = X1f x u2w;
// out = irfft(X2f + s2xS1f) + s2 x gelu(irfft(U1f)) [recomputed] + const.
// Block per (n, 4-row tile); 256 threads = 1 pixel each.
// ---------------------------------------------------------------------------
__global__ __launch_bounds__(256) void final_kernel(const float2* __restrict__ Etab,
                                                    const float2* __restrict__ U1f,
                                                    const float2* __restrict__ S1f,
                                                    const float2* __restrict__ Xg,
                                                    const float* __restrict__ u2wr, const float* __restrict__ u2wi,
                                                    const float* __restrict__ s1b,
                                                    const float* __restrict__ s2w, const float* __restrict__ s2b,
                                                    float* __restrict__ out){
  int n = blockIdx.x >> 4, tile = blockIdx.x & 15, y0 = tile*4;
  int tid = threadIdx.x;
  __shared__ float2 s_e[64][8];
  __shared__ float2 s_u1[32][64];
  __shared__ float2 s_T[32][4][8];
  __shared__ float2 s_os[4][64];
  __shared__ float2 s_tmp[4][4][8];
  __shared__ float  s_w2[128], s_s1b[32], s_b2[4];
  for (int e = tid; e < 512; e += 256) ((float2*)s_e)[e] = Etab[e];
  for (int k = tid; k < 2048; k += 256) ((float2*)s_u1)[k] = U1f[(size_t)n*2048 + k];
  if (tid < 128) s_w2[tid] = s2w[tid];
  else if (tid < 160) s_s1b[tid-128] = s1b[tid-128];
  else if (tid < 164) s_b2[tid-160] = s2b[tid-160];
  __syncthreads();
  // phase 1: per-channel y-transform for this tile's 4 rows (wf folded)
  for (int e = tid; e < 1024; e += 256){
    int c = e >> 5, yy = (e >> 3) & 3, kx = e & 7;
    int y = y0 + yy;
    float wf = (kx ? 2.0f : 1.0f) * (1.0f/4096.0f);
    float ar = 0.f, ai = 0.f;
    for (int ky = 0; ky < 8; ++ky){
      float2 cs = s_e[y][ky];
      float2 g = s_u1[c][ky*8+kx];
      ar += g.x*cs.x - g.y*cs.y;
      ai += g.x*cs.y + g.y*cs.x;
    }
    s_T[c][yy][kx] = f2(ar*wf, ai*wf);
  }
  // phase 2: outspec[o2][m] = sum_o1 X1f*u2w + sum_o1 s2w*S1f
  {
    int o2 = tid >> 6, m = tid & 63;
    float prm = ((m & 7)==0 && m) ? 0.5f : 1.0f;
    float pim = m ? prm : 0.0f;
    float dc = (m == 0) ? 4096.0f : 0.0f;
    float cr = 0.f, ci = 0.f;
    for (int o1 = 0; o1 < 32; ++o1){
      float2 xg = Xg[((size_t)n*32 + o1)*NM + m];
      float2 sf = S1f[((size_t)n*32 + o1)*NM + m];
      float Xr = xg.x + sf.x*prm + dc*s_s1b[o1];
      float Xi = xg.y + sf.y*pim;
      size_t wb = ((size_t)(o1*IN_CH + o2))*NM + m;
      float wr = u2wr[wb], wi = u2wi[wb];
      float sw = s_w2[o2*32 + o1];
      cr += Xr*wr - Xi*wi + sw*sf.x;
      ci += Xr*wi + Xi*wr + sw*sf.y;
    }
    s_os[o2][m] = f2(cr, ci);
  }
  __syncthreads();
  // phase 3: outspec y-transform
  if (tid < 128){
    int o2 = tid >> 5, yy = (tid >> 3) & 3, kx = tid & 7;
    int y = y0 + yy;
    float wf = (kx ? 2.0f : 1.0f) * (1.0f/4096.0f);
    float tr=0.f, ti=0.f;
    for (int ky = 0; ky < 8; ++ky){
      float2 cs = s_e[y][ky];
      float2 g = s_os[o2][ky*8+kx];
      tr += g.x*cs.x - g.y*cs.y;
      ti += g.x*cs.y + g.y*cs.x;
    }
    s_tmp[o2][yy][kx] = f2(tr*wf, ti*wf);
  }
  __syncthreads();
  // phase 4: pixels (1 per thread)
  int yy = tid >> 6, xx = tid & 63;
  float2 ce[8];
  #pragma unroll
  for (int k = 0; k < 8; ++k) ce[k] = s_e[xx][k];
  float a0 = s_b2[0], a1 = s_b2[1], a2 = s_b2[2], a3 = s_b2[3];
  for (int c = 0; c < 32; ++c){
    float b = s_s1b[c];
    a0 += s_w2[c]*b; a1 += s_w2[32+c]*b; a2 += s_w2[64+c]*b; a3 += s_w2[96+c]*b;
  }
  for (int c = 0; c < 32; ++c){
    const float4* tp = (const float4*)&s_T[c][yy][0];
    float4 t0 = tp[0], t1 = tp[1], t2 = tp[2], t3 = tp[3];
    float vu = t0.x*ce[0].x - t0.y*ce[0].y + t0.z*ce[1].x - t0.w*ce[1].y
             + t1.x*ce[2].x - t1.y*ce[2].y + t1.z*ce[3].x - t1.w*ce[3].y
             + t2.x*ce[4].x - t2.y*ce[4].y + t2.z*ce[5].x - t2.w*ce[5].y
             + t3.x*ce[6].x - t3.y*ce[6].y + t3.z*ce[7].x - t3.w*ce[7].y;
    float g = 0.5f * vu * (1.0f + erff(vu * 0.70710678f));
    a0 += s_w2[c]*g; a1 += s_w2[32+c]*g; a2 += s_w2[64+c]*g; a3 += s_w2[96+c]*g;
  }
  float sp[4];
  #pragma unroll
  for (int o2 = 0; o2 < 4; ++o2){
    const float4* tp = (const float4*)&s_tmp[o2][yy][0];
    float4 t0 = tp[0], t1 = tp[1], t2 = tp[2], t3 = tp[3];
    sp[o2] = t0.x*ce[0].x - t0.y*ce[0].y + t0.z*ce[1].x - t0.w*ce[1].y
           + t1.x*ce[2].x - t1.y*ce[2].y + t1.z*ce[3].x - t1.w*ce[3].y
           + t2.x*ce[4].x - t2.y*ce[4].y + t2.z*ce[5].x - t2.w*ce[5].y
           + t3.x*ce[6].x - t3.y*ce[6].y + t3.z*ce[7].x - t3.w*ce[7].y;
  }
  int p = (y0 + yy)*64 + xx;
  float* ob = out + (size_t)n*IN_CH*NPIX;
  ob[p]          = a0 + sp[0];
  ob[NPIX + p]   = a1 + sp[1];
  ob[2*NPIX + p] = a2 + sp[2];
  ob[3*NPIX + p] = a3 + sp[3];
}

extern "C" void kernel_launch(void* const* d_in, const int* in_sizes, int n_in,
                              void* d_out, int out_size, void* d_ws, size_t ws_size,
                              hipStream_t stream) {
  (void)in_sizes; (void)n_in; (void)out_size; (void)ws_size;
  const float* v    = (const float*)d_in[0];
  const float* qwr  = (const float*)d_in[1];
  const float* qwi  = (const float*)d_in[2];
  const float* kwr  = (const float*)d_in[3];
  const float* kwi  = (const float*)d_in[4];
  const float* vwr  = (const float*)d_in[5];
  const float* vwi  = (const float*)d_in[6];
  const float* u1wr = (const float*)d_in[7];
  const float* u1wi = (const float*)d_in[8];
  const float* u2wr = (const float*)d_in[9];
  const float* u2wi = (const float*)d_in[10];
  const float* s1w  = (const float*)d_in[11];
  const float* s1b  = (const float*)d_in[12];
  const float* s2w  = (const float*)d_in[13];
  const float* s2b  = (const float*)d_in[14];
  float* out = (float*)d_out;

  float* ws = (float*)d_ws;
  size_t off = 0;
  float2* Etab =(float2*)(ws + off); off += 1024;                       // 512 float2
  float2* Vf   = (float2*)(ws + off); off += (size_t)NS*IN_CH*NM*2;     // 32768
  float2* G2   = (float2*)(ws + off); off += (size_t)65536*2;           // 131072
  float*  Gdc  =          (ws + off); off += 4096;
  float*  A    =          (ws + off); off += 16384;
  float2* Uf   = (float2*)(ws + off); off += (size_t)NS*NM*HD*2;        // 2097152
  float2* U1f  = (float2*)(ws + off); off += (size_t)NS*HIDC*NM*2;      // 262144
  float2* S1f  = (float2*)(ws + off); off += (size_t)NS*HIDC*NM*2;      // 262144
  float2* Xg   = (float2*)(ws + off); off += (size_t)NS*HIDC*NM*2;      // 262144
  float4* u1wT = (float4*)(ws + off); off += (size_t)524288*4;          // 2097152

  twiddle_kernel<<<1, 512, 0, stream>>>(Etab);
  fwd_dft_kernel<<<NS*IN_CH, 256, 0, stream>>>(v, Etab, Vf);
  gram_kernel<<<64, 256, 0, stream>>>(qwr, qwi, kwr, kwi, G2, Gdc);
  u1t_kernel<<<2048, 256, 0, stream>>>(u1wr, u1wi, u1wT);
  attn_kernel<<<512, 256, 0, stream>>>(Vf, G2, Gdc, A);
  uspec_kernel<<<512, 256, 0, stream>>>(Vf, vwr, vwi, A, Uf);
  mix1_kernel<<<1024, 128, 0, stream>>>(Uf, u1wT, s1w, U1f, S1f);
  xg_kernel<<<NS*HIDC, 256, 0, stream>>>(Etab, U1f, Xg);
  final_kernel<<<NS*16, 256, 0, stream>>>(Etab, U1f, S1f, Xg, u2wr, u2wi, s1b, s2w, s2b, out);
}